// Round 6
// baseline (250.740 us; speedup 1.0000x reference)
//
#include <hip/hip_runtime.h>
#include <hip/hip_bf16.h>
#include <math.h>

// ---------------------------------------------------------------------------
// RotSSM: out[b,Do,t] = C2 @ scan(M @ u)[.,b,t] + D ⊙ u[b,.,t]
// Single main kernel with decoupled look-back (all 1024 blocks resident:
// LDS 33792 B -> 4 blocks/CU x 256 CUs = 1024 = grid, spin is deadlock-free):
//   stage u -> GEMM1 -> local scan (W in LDS) -> publish Tot_c + flag ->
//   spin on predecessors -> carry = sum (a^32)^k Tot -> z += a^{t+1} carry ->
//   GEMM2 -> out. No states round-trip, no GEMM1 recompute, no serial k2.
// Frag formulas (HW-verified): A[m=L&15][k=(L>>4)*8+j], B[k][n=L&15],
// D col=L&15, row=(L>>4)*4+reg.
// ---------------------------------------------------------------------------

typedef __attribute__((ext_vector_type(8))) short short8;   // 8 bf16 (4 VGPRs)
typedef __attribute__((ext_vector_type(4))) float f32x4;

#define TLEN 4096
#define LCH 32
#define NCH 128
#define BSZ 8
#define LDK 264          // shorts per [t] row (256 + 8 pad, 16B-aligned rows)
#define LDW 132          // dwords per [t] row

// workspace float offsets
constexpr int MB_OFF   = 0;                           // M bf16 row-major [256][256]
constexpr int CB_OFF   = 32768;                       // C2 bf16 row-major
constexpr int A1_OFF   = 65536;                       // a^1 [128] float2
constexpr int AP_OFF   = 65792;                       // a^{t+1}, t in [0,32): [32][128] float2
constexpr int ALP_OFF  = AP_OFF + 32 * 256;           // (a^32)^k, k in [0,128): [128][128] float2
constexpr int TOT_OFF  = ALP_OFF + 128 * 256;         // Tot [128][8][128] float2
constexpr int FLG_OFF  = TOT_OFF + NCH * BSZ * 256;   // flags [8][128] int
constexpr int PL_OFF   = FLG_OFF + BSZ * NCH;         // P [64][4][4]
constexpr int NORM_OFF = PL_OFF + 1024;               // norm [64]

__device__ __forceinline__ float bfbits2f(unsigned int bits16) {
  union { unsigned int u; float f; } v; v.u = bits16 << 16; return v.f;
}
__device__ __forceinline__ unsigned int f2bfbits(float f) {
  union { float f; unsigned int u; } v; v.f = f;
  return (v.u + 0x7fffu + ((v.u >> 16) & 1u)) >> 16;   // RNE, finite inputs
}
__device__ __forceinline__ unsigned int pack2(float x, float y) {
  return f2bfbits(x) | (f2bfbits(y) << 16);
}

// ---------------------------------------------------------------------------
// K0a: gamma, norm, expm(skew), a^1, a^{t+1} table, (a^32)^k table, zero flags.
// 1 block.
// ---------------------------------------------------------------------------
__global__ __launch_bounds__(256) void k0a_precompute(
    const float* __restrict__ thetas_log, const float* __restrict__ P_param,
    const float* __restrict__ B_param, const float* __restrict__ gamma_log,
    float* __restrict__ ws) {
  __shared__ float tracep[64][4];
  __shared__ double gamma_d[64];
  const int tid = threadIdx.x;
  // zero look-back flags (ws is poisoned to 0xAA each launch)
  {
    int* fl = (int*)(ws + FLG_OFF);
    fl[tid] = 0; fl[tid + 256] = 0; fl[tid + 512] = 0; fl[tid + 768] = 0;
  }
  {
    const float4* bp = (const float4*)(B_param + tid * 256);
    float s = 0.f;
#pragma unroll 8
    for (int i = 0; i < 64; ++i) {
      float4 v = bp[i];
      s += v.x * v.x + v.y * v.y + v.z * v.z + v.w * v.w;
    }
    tracep[tid >> 2][tid & 3] = s;
  }
  __syncthreads();
  if (tid < 64) {
    int h = tid;
    double g = exp(-exp((double)gamma_log[h]));
    gamma_d[h] = g;
    double tr = (double)tracep[h][0] + tracep[h][1] + tracep[h][2] + tracep[h][3];
    ws[NORM_OFF + h] = (float)sqrt((1.0 - g * g) / tr);
    double A[4][4], E[4][4], Tm[4][4];
    for (int i = 0; i < 4; ++i)
      for (int j = 0; j < 4; ++j)
        A[i][j] = (double)P_param[h * 16 + i * 4 + j] - (double)P_param[h * 16 + j * 4 + i];
    double fro = 0.0;
    for (int i = 0; i < 4; ++i) for (int j = 0; j < 4; ++j) fro += A[i][j] * A[i][j];
    fro = sqrt(fro);
    int s = 0;
    while (fro > 0.25 && s < 30) { fro *= 0.5; ++s; }
    double scl = 1.0;
    for (int q2 = 0; q2 < s; ++q2) scl *= 0.5;
    for (int i = 0; i < 4; ++i) for (int j = 0; j < 4; ++j) A[i][j] *= scl;
    for (int i = 0; i < 4; ++i)
      for (int j = 0; j < 4; ++j) { E[i][j] = (i == j) ? 1.0 : 0.0; Tm[i][j] = E[i][j]; }
    for (int k = 1; k <= 16; ++k) {
      double Tn[4][4];
      for (int i = 0; i < 4; ++i)
        for (int j = 0; j < 4; ++j) {
          double acc = 0.0;
          for (int m = 0; m < 4; ++m) acc += Tm[i][m] * A[m][j];
          Tn[i][j] = acc / (double)k;
        }
      for (int i = 0; i < 4; ++i)
        for (int j = 0; j < 4; ++j) { Tm[i][j] = Tn[i][j]; E[i][j] += Tn[i][j]; }
    }
    for (int q2 = 0; q2 < s; ++q2) {
      double E2[4][4];
      for (int i = 0; i < 4; ++i)
        for (int j = 0; j < 4; ++j) {
          double acc = 0.0;
          for (int m = 0; m < 4; ++m) acc += E[i][m] * E[m][j];
          E2[i][j] = acc;
        }
      for (int i = 0; i < 4; ++i) for (int j = 0; j < 4; ++j) E[i][j] = E2[i][j];
    }
    for (int i = 0; i < 4; ++i)
      for (int j = 0; j < 4; ++j) ws[PL_OFF + h * 16 + i * 4 + j] = (float)E[i][j];
  }
  __syncthreads();
  if (tid < 128) {
    int h = tid >> 1, p = tid & 1;
    double th = exp((double)thetas_log[h * 2 + p]);
    double g = gamma_d[h];
    double ar = g * cos(th), ai = g * sin(th);
    ((float2*)(ws + A1_OFF))[tid] = make_float2((float)ar, (float)ai);
    float2* Apw = (float2*)(ws + AP_OFF);
    double xr = ar, xi = ai;
    Apw[tid] = make_float2((float)xr, (float)xi);         // a^1 (t=0)
    for (int j = 2; j <= 32; ++j) {
      double nr = xr * ar - xi * ai, ni = xr * ai + xi * ar;
      xr = nr; xi = ni;
      Apw[(j - 1) * 128 + tid] = make_float2((float)xr, (float)xi);
    }
    double br = xr, bi = xi;   // a^32
    float2* ALp = (float2*)(ws + ALP_OFF);
    xr = 1.0; xi = 0.0;
    ALp[tid] = make_float2(1.f, 0.f);
    for (int k = 1; k < NCH; ++k) {
      double nr = xr * br - xi * bi, ni = xr * bi + xi * br;
      xr = nr; xi = ni;
      ALp[k * 128 + tid] = make_float2((float)xr, (float)xi);
    }
  }
}

// ---------------------------------------------------------------------------
// K0b: M = norm*(P@B), C2 = C@blockdiag(P^T) -> plain row-major bf16.
// ---------------------------------------------------------------------------
__global__ __launch_bounds__(256) void k0b_mats(
    const float* __restrict__ B_param, const float* __restrict__ C,
    float* __restrict__ ws) {
  const float* Pl  = ws + PL_OFF;
  const float* nrm = ws + NORM_OFF;
  unsigned short* Mbf = (unsigned short*)(ws + MB_OFF);
  unsigned short* Cbf = (unsigned short*)(ws + CB_OFF);
  const int blk = blockIdx.x, tid = threadIdx.x;
  if (blk < 16) {
    for (int rr = 0; rr < 16; ++rr) {
      int r = blk * 16 + rr, h = r >> 2, N = r & 3;
      float acc = 0.f;
      for (int n = 0; n < 4; ++n)
        acc += Pl[h * 16 + N * 4 + n] * B_param[(h * 4 + n) * 256 + tid];
      Mbf[r * 256 + tid] = (unsigned short)f2bfbits(nrm[h] * acc);
    }
  } else {
    int h = tid >> 2, N = tid & 3;       // tid = state-column index k = 4h+N
    for (int rr = 0; rr < 16; ++rr) {
      int Do = (blk - 16) * 16 + rr;
      float acc = 0.f;
      for (int n = 0; n < 4; ++n)
        acc += C[Do * 256 + (tid & ~3) + n] * Pl[h * 16 + N * 4 + n];
      Cbf[Do * 256 + tid] = (unsigned short)f2bfbits(acc);
    }
  }
}

// ---------------------------------------------------------------------------
// Main: stage u -> GEMM1 -> scan -> publish -> lookback -> correct -> GEMM2.
// Grid (NCH, BSZ) = 1024 blocks, all resident (4/CU). LDS 33792 B.
// ---------------------------------------------------------------------------
__global__ __launch_bounds__(256, 4) void main_rotssm(
    const float* __restrict__ u, const float* __restrict__ Dv,
    float* __restrict__ ws, float* __restrict__ out) {
  __shared__ __align__(16) unsigned char smem[2 * LCH * LDK * 2];
  unsigned short* us = (unsigned short*)smem;                       // u tile
  unsigned int*   wd = (unsigned int*)(smem + LCH * LDK * 2);       // W/z tile

  const int c = blockIdx.x, b = blockIdx.y;
  const int t0 = c * LCH;
  const int tid = threadIdx.x;
  const int L = tid & 63;
  const int w = __builtin_amdgcn_readfirstlane(tid >> 6);
  const int qh = L >> 4, l15 = L & 15;

  // ---- stage u[d][t0+t] -> us[t][d ^ ((t&3)<<3)] ----
  {
    const int kbase = tid >> 3, t4 = (tid & 7) * 4;
#pragma unroll
    for (int i = 0; i < 8; ++i) {
      int d = kbase + i * 32;
      float4 v = *(const float4*)(u + (size_t)(b * 256 + d) * TLEN + t0 + t4);
      float vv[4] = {v.x, v.y, v.z, v.w};
#pragma unroll
      for (int dt = 0; dt < 4; ++dt)
        us[(t4 + dt) * LDK + (d ^ (dt << 3))] = (unsigned short)f2bfbits(vv[dt]);
    }
  }
  __syncthreads();

  // ---- GEMM1: W[256][32] = M @ u_tile ----
  f32x4 acc[4][2];
#pragma unroll
  for (int rt = 0; rt < 4; ++rt)
#pragma unroll
    for (int tt = 0; tt < 2; ++tt) acc[rt][tt] = (f32x4){0.f, 0.f, 0.f, 0.f};
  {
    const unsigned short* Mbf = (const unsigned short*)(ws + MB_OFF);
#pragma unroll
    for (int ks = 0; ks < 8; ++ks) {
      short8 af[4], bf[2];
#pragma unroll
      for (int rt = 0; rt < 4; ++rt)
        af[rt] = *(const short8*)(Mbf + (size_t)(w * 64 + rt * 16 + l15) * 256 + ks * 32 + qh * 8);
#pragma unroll
      for (int tt = 0; tt < 2; ++tt) {
        int row = tt * 16 + l15;
        int col = (ks * 32 + qh * 8) ^ ((row & 3) << 3);
        bf[tt] = *(const short8*)(us + row * LDK + col);
      }
#pragma unroll
      for (int rt = 0; rt < 4; ++rt)
#pragma unroll
        for (int tt = 0; tt < 2; ++tt)
          acc[rt][tt] = __builtin_amdgcn_mfma_f32_16x16x32_bf16(af[rt], bf[tt], acc[rt][tt], 0, 0, 0);
    }
  }

  // ---- W -> wd[t][p] pair-packed bf16 ----
#pragma unroll
  for (int rt = 0; rt < 4; ++rt) {
    int pbase = w * 32 + rt * 8 + qh * 2;
#pragma unroll
    for (int tt = 0; tt < 2; ++tt) {
      int t = tt * 16 + l15;
      f32x4 a4 = acc[rt][tt];
      *(uint2*)&wd[t * LDW + pbase] = make_uint2(pack2(a4[0], a4[1]), pack2(a4[2], a4[3]));
    }
  }
  __syncthreads();

  // ---- local scan (zero init); store unseeded z_t; publish Tot ----
  if (tid < 128) {
    const int p = tid;
    float2 a = ((const float2*)(ws + A1_OFF))[p];
    float zr = 0.f, zi = 0.f;
#pragma unroll
    for (int t = 0; t < LCH; ++t) {
      unsigned int wv = wd[t * LDW + p];
      float wr = bfbits2f(wv & 0xffffu), wi = bfbits2f(wv >> 16);
      float nr = fmaf(a.x, zr, fmaf(-a.y, zi, wr));
      float ni = fmaf(a.x, zi, fmaf(a.y, zr, wi));
      zr = nr; zi = ni;
      wd[t * LDW + p] = pack2(zr, zi);
    }
    ((float2*)(ws + TOT_OFF))[(c * BSZ + b) * 128 + p] = make_float2(zr, zi);
    __threadfence();                       // device-scope: Tot visible before flag
  }
  __syncthreads();
  if (tid == 0)
    __hip_atomic_store((int*)(ws + FLG_OFF) + b * NCH + c, 1,
                       __ATOMIC_RELEASE, __HIP_MEMORY_SCOPE_AGENT);

  // ---- look-back: wait for predecessors (parallel poll), then carry ----
  if (c > 0) {
    if (tid < c) {
      const int* fl = (const int*)(ws + FLG_OFF) + b * NCH + tid;
      while (__hip_atomic_load(fl, __ATOMIC_ACQUIRE, __HIP_MEMORY_SCOPE_AGENT) == 0)
        __builtin_amdgcn_s_sleep(1);
    }
    __syncthreads();
    if (tid < 128) {
      const int p = tid;
      const float2* ALp = (const float2*)(ws + ALP_OFF);
      const float2* Tot = (const float2*)(ws + TOT_OFF);
      float cr = 0.f, ci = 0.f;
      for (int cp = 0; cp < c; ++cp) {
        float2 al = ALp[(c - 1 - cp) * 128 + p];
        float2 tv = Tot[(cp * BSZ + b) * 128 + p];
        cr = fmaf(al.x, tv.x, fmaf(-al.y, tv.y, cr));
        ci = fmaf(al.x, tv.y, fmaf(al.y, tv.x, ci));
      }
      // correction: z_t += a^{t+1} * carry
      const float2* Apw = (const float2*)(ws + AP_OFF);
#pragma unroll
      for (int t = 0; t < LCH; ++t) {
        float2 ap = Apw[t * 128 + p];
        unsigned int wv = wd[t * LDW + p];
        float sr = fmaf(ap.x, cr, fmaf(-ap.y, ci, bfbits2f(wv & 0xffffu)));
        float si = fmaf(ap.x, ci, fmaf(ap.y, cr, bfbits2f(wv >> 16)));
        wd[t * LDW + p] = pack2(sr, si);
      }
    }
  }
  __syncthreads();

  // ---- GEMM2: out_tile = C2 @ Z ----
#pragma unroll
  for (int rt = 0; rt < 4; ++rt)
#pragma unroll
    for (int tt = 0; tt < 2; ++tt) acc[rt][tt] = (f32x4){0.f, 0.f, 0.f, 0.f};
  {
    const unsigned short* Cbf = (const unsigned short*)(ws + CB_OFF);
    const unsigned short* zs  = (const unsigned short*)wd;
#pragma unroll
    for (int ks = 0; ks < 8; ++ks) {
      short8 af[4], bf[2];
#pragma unroll
      for (int rt = 0; rt < 4; ++rt)
        af[rt] = *(const short8*)(Cbf + (size_t)(w * 64 + rt * 16 + l15) * 256 + ks * 32 + qh * 8);
#pragma unroll
      for (int tt = 0; tt < 2; ++tt)
        bf[tt] = *(const short8*)(zs + (tt * 16 + l15) * LDK + ks * 32 + qh * 8);
#pragma unroll
      for (int rt = 0; rt < 4; ++rt)
#pragma unroll
        for (int tt = 0; tt < 2; ++tt)
          acc[rt][tt] = __builtin_amdgcn_mfma_f32_16x16x32_bf16(af[rt], bf[tt], acc[rt][tt], 0, 0, 0);
    }
  }

  // ---- epilogue: out = acc + D ⊙ u (u bf16 from us tile) ----
#pragma unroll
  for (int rt = 0; rt < 4; ++rt) {
    int Dbase = w * 64 + rt * 16 + qh * 4;
    float dv[4];
#pragma unroll
    for (int q = 0; q < 4; ++q) dv[q] = Dv[Dbase + q];
#pragma unroll
    for (int tt = 0; tt < 2; ++tt) {
      int t = tt * 16 + l15;
      f32x4 a4 = acc[rt][tt];
      size_t obase = (size_t)(b * 256 + Dbase) * TLEN + t0 + t;
#pragma unroll
      for (int q = 0; q < 4; ++q) {
        float uu = bfbits2f(us[t * LDK + ((Dbase + q) ^ ((t & 3) << 3))]);
        out[obase + (size_t)q * TLEN] = a4[q] + dv[q] * uu;
      }
    }
  }
}

extern "C" void kernel_launch(void* const* d_in, const int* in_sizes, int n_in,
                              void* d_out, int out_size, void* d_ws, size_t ws_size,
                              hipStream_t stream) {
  const float* u          = (const float*)d_in[0];
  const float* thetas_log = (const float*)d_in[1];
  const float* P_param    = (const float*)d_in[2];
  const float* B_param    = (const float*)d_in[3];
  const float* C          = (const float*)d_in[4];
  const float* Dvec       = (const float*)d_in[5];
  const float* gamma_log  = (const float*)d_in[6];
  float* out = (float*)d_out;
  float* ws  = (float*)d_ws;

  hipLaunchKernelGGL(k0a_precompute, dim3(1), dim3(256), 0, stream,
                     thetas_log, P_param, B_param, gamma_log, ws);
  hipLaunchKernelGGL(k0b_mats, dim3(32), dim3(256), 0, stream, B_param, C, ws);
  hipLaunchKernelGGL(main_rotssm, dim3(NCH, BSZ), dim3(256), 0, stream,
                     u, Dvec, ws, out);
}